// Round 5
// baseline (97.460 us; speedup 1.0000x reference)
//
#include <hip/hip_runtime.h>

// Elementwise: out[i] = x[i] > 0 ? x[i]*x[i] : x[i]
// N = 2^26 fp32. Memory-bound: 536.9 MB total traffic. Ceiling ~85us @ 6.3 TB/s.
// R1: grid-stride float4, 107.7us = 4.99 TB/s.
// R3: unroll x4 far-apart streams + nt = 118us REGRESSION.
// R4: block-contiguous unroll x4, 16KiB tile/block = 96.6us = 5.56 TB/s.
// R5: unroll x8, 32KiB tile/block (8 loads in flight/wave, 8192 blocks).

typedef float f4 __attribute__((ext_vector_type(4)));

__global__ __launch_bounds__(256) void sq_pos_kernel(const f4* __restrict__ x,
                                                     f4* __restrict__ out) {
    // Block tile: 8*256 f4 = 32 KiB. Thread t covers tile + t + k*256.
    const long long base = (long long)blockIdx.x * (8 * 256) + threadIdx.x;

    f4 v[8];
#pragma unroll
    for (int k = 0; k < 8; ++k) v[k] = x[base + k * 256];

#pragma unroll
    for (int k = 0; k < 8; ++k) {
        f4 r = v[k];
        r.x = r.x > 0.0f ? r.x * r.x : r.x;
        r.y = r.y > 0.0f ? r.y * r.y : r.y;
        r.z = r.z > 0.0f ? r.z * r.z : r.z;
        r.w = r.w > 0.0f ? r.w * r.w : r.w;
        out[base + k * 256] = r;
    }
}

// Generic fallback for sizes not divisible by 8192 floats (not hit for N=2^26).
__global__ void sq_pos_tail(const float* __restrict__ x, float* __restrict__ o,
                            long long start, long long n) {
    long long i = start + (long long)blockIdx.x * blockDim.x + threadIdx.x;
    if (i < n) { float v = x[i]; o[i] = v > 0.0f ? v * v : v; }
}

extern "C" void kernel_launch(void* const* d_in, const int* in_sizes, int n_in,
                              void* d_out, int out_size, void* d_ws, size_t ws_size,
                              hipStream_t stream) {
    const float* xf = (const float*)d_in[0];
    float* of = (float*)d_out;
    long long n = in_sizes[0];

    // Main kernel: each block handles 2048 f4 = 8192 floats.
    long long nblocks = n / 8192;
    if (nblocks > 0) {
        sq_pos_kernel<<<(int)nblocks, 256, 0, stream>>>((const f4*)xf, (f4*)of);
    }
    long long done = nblocks * 8192;
    if (done < n) {
        long long rem = n - done;
        int tgrid = (int)((rem + 255) / 256);
        sq_pos_tail<<<tgrid, 256, 0, stream>>>(xf, of, done, n);
    }
}

// Round 6
// 81.116 us; speedup vs baseline: 1.2015x; 1.2015x over previous
//
#include <hip/hip_runtime.h>

// Elementwise: out[i] = x[i] > 0 ? x[i]*x[i] : x[i]
// N = 2^26 fp32. Memory-bound: 536.9 MB total traffic. Copy-ceiling ~85us @ 6.29 TB/s.
// R1: grid-stride float4, 107.7us = 4.99 TB/s.
// R3: unroll x4 far-apart streams + nt(load+store) = 118us REGRESSION (confounded).
// R4: block-contiguous unroll x4, 16KiB tile/block = 96.6us = 5.56 TB/s.  <- best
// R5: unroll x8 = 97.5us, flat -> MLP saturated, not the limiter.
// R6: R4 structure + nt STORES ONLY (isolated cache-policy lever).

typedef float f4 __attribute__((ext_vector_type(4)));

__global__ __launch_bounds__(256) void sq_pos_kernel(const f4* __restrict__ x,
                                                     f4* __restrict__ out) {
    // Block tile: 4*256 f4 = 16 KiB. Thread t covers tile + t + k*256.
    const long long base = (long long)blockIdx.x * (4 * 256) + threadIdx.x;

    f4 v0 = x[base];
    f4 v1 = x[base + 256];
    f4 v2 = x[base + 512];
    f4 v3 = x[base + 768];

    auto f = [](f4 v) -> f4 {
        f4 r;
        r.x = v.x > 0.0f ? v.x * v.x : v.x;
        r.y = v.y > 0.0f ? v.y * v.y : v.y;
        r.z = v.z > 0.0f ? v.z * v.z : v.z;
        r.w = v.w > 0.0f ? v.w * v.w : v.w;
        return r;
    };

    __builtin_nontemporal_store(f(v0), &out[base]);
    __builtin_nontemporal_store(f(v1), &out[base + 256]);
    __builtin_nontemporal_store(f(v2), &out[base + 512]);
    __builtin_nontemporal_store(f(v3), &out[base + 768]);
}

// Generic fallback for sizes not divisible by 4096 floats (not hit for N=2^26).
__global__ void sq_pos_tail(const float* __restrict__ x, float* __restrict__ o,
                            long long start, long long n) {
    long long i = start + (long long)blockIdx.x * blockDim.x + threadIdx.x;
    if (i < n) { float v = x[i]; o[i] = v > 0.0f ? v * v : v; }
}

extern "C" void kernel_launch(void* const* d_in, const int* in_sizes, int n_in,
                              void* d_out, int out_size, void* d_ws, size_t ws_size,
                              hipStream_t stream) {
    const float* xf = (const float*)d_in[0];
    float* of = (float*)d_out;
    long long n = in_sizes[0];

    // Main kernel: each block handles 1024 f4 = 4096 floats.
    long long nblocks = n / 4096;
    if (nblocks > 0) {
        sq_pos_kernel<<<(int)nblocks, 256, 0, stream>>>((const f4*)xf, (f4*)of);
    }
    long long done = nblocks * 4096;
    if (done < n) {
        long long rem = n - done;
        int tgrid = (int)((rem + 255) / 256);
        sq_pos_tail<<<tgrid, 256, 0, stream>>>(xf, of, done, n);
    }
}